// Round 5
// baseline (300.848 us; speedup 1.0000x reference)
//
#include <hip/hip_runtime.h>
#include <math.h>

namespace {

constexpr int N_PTS  = 1000000;
constexpr int C_CLS  = 20;
constexpr int N_B    = 4;
constexpr int L_LAB  = 200;
constexpr int LW     = L_LAB + 1;   // 201
constexpr int N_INST = 64;
constexpr int M_PTS  = 300000;
constexpr int T_PROP = 320000;
constexpr int IGN    = -100;
constexpr int PREP   = 128;

// ---- workspace layout (bytes) ----
constexpr size_t OFF_G      = 0;       // 5 doubles (reserve 64B)
constexpr size_t OFF_INTER  = 64;      // 64 doubles each
constexpr size_t OFF_UP     = 576;
constexpr size_t OFF_UG     = 1088;
constexpr size_t OFF_WBS    = 1600;
constexpr size_t OFF_SN     = 2112;
constexpr size_t OFF_HFULL  = 2624;    // 804 ints
constexpr size_t OFF_HMASK  = 5840;    // 804 ints
constexpr size_t OFF_IHIST  = 9056;    // 64*201 ints = 51456 B
constexpr size_t OFF_FLAGS  = 60512;   // 64 ints
constexpr size_t ZERO_BYTES = 60768;
constexpr size_t OFF_META   = 60800;   // 300000 ushorts
constexpr size_t WS_REQUIRED = OFF_META + (size_t)M_PTS * 2;

__device__ __forceinline__ float waveSumF(float v) {
  #pragma unroll
  for (int off = 32; off > 0; off >>= 1) v += __shfl_down(v, off, 64);
  return v;
}
__device__ __forceinline__ int waveMaxI(int v) {
  #pragma unroll
  for (int off = 32; off > 0; off >>= 1) v = max(v, __shfl_down(v, off, 64));
  return v;
}

// ---------------------------------------------------------------------------
// K_A: one dispatch, four independent jobs split by blockIdx.x.
//   [0, 256)    : hist_full[B][LW] over N points (int4 scan, LDS hist)
//   [256, 512)  : proposal histogram -> inst_hist[64][LW] (global atomics)
//   [512, 768)  : hist_mask[B][LW] over M points + meta16 (batched gathers)
//   [768, ...)  : per-point losses, 256-point tile per block, LDS-staged
//                 coalesced loads (lane-contiguous float4 everywhere)
// ---------------------------------------------------------------------------
constexpr int PB_HF   = 256;
constexpr int PB_PROP = 256;
constexpr int PB_HM   = 256;
constexpr int PB_PRE  = PB_HF + PB_PROP + PB_HM;           // 768
constexpr int PT_TILES = (N_PTS + 255) / 256;              // 3907
constexpr int A_BLOCKS = PB_PRE + PT_TILES;

// LDS tile: scores [256][21] floats (5376) + coords 768 + ptoff 768 + info3 768
constexpr int LDS_SC = 256 * 21;       // stride 21 -> conflict-free reads
constexpr int LDS_CO = LDS_SC;         // 768 floats, [p*3+c]
constexpr int LDS_OF = LDS_CO + 768;
constexpr int LDS_IN = LDS_OF + 768;
constexpr int LDS_FLOATS = LDS_IN + 768;   // 7680 floats = 30720 B

__global__ __launch_bounds__(256) void k_A(const float* __restrict__ scores,
                                           const float* __restrict__ pt_off,
                                           const float* __restrict__ info,
                                           const float* __restrict__ coords,
                                           const int* __restrict__ sem_lab,
                                           const int* __restrict__ inst_lab,
                                           const int* __restrict__ obj_idx,
                                           const int* __restrict__ batch_ids,
                                           const int* __restrict__ prop_idx,
                                           const int* __restrict__ prop_off,
                                           const int* __restrict__ batch_off,
                                           double* __restrict__ g,
                                           int* __restrict__ hist_full,
                                           int* __restrict__ hist_mask,
                                           int* __restrict__ inst_hist,
                                           unsigned short* __restrict__ meta,
                                           int write_meta) {
  __shared__ float s_f[LDS_FLOATS];
  int* sh = reinterpret_cast<int*>(s_f);     // alias for histogram jobs
  const int bx = blockIdx.x;
  const int t  = threadIdx.x;

  if (bx < PB_HF) {
    // ================= hist_full over N points =================
    for (int k = t; k < N_B * LW; k += blockDim.x) sh[k] = 0;
    __syncthreads();
    const int b1 = batch_off[1], b2 = batch_off[2], b3 = batch_off[3];
    const int4* il4p = reinterpret_cast<const int4*>(inst_lab);
    const int nq = N_PTS / 4;
    for (int q = bx * blockDim.x + t; q < nq; q += PB_HF * blockDim.x) {
      const int4 v = il4p[q];
      const int p = q * 4;
      const int ils[4] = { v.x, v.y, v.z, v.w };
      #pragma unroll
      for (int k = 0; k < 4; ++k) {
        const int lab = (ils[k] == IGN) ? 0 : (ils[k] + 1);
        const int pp = p + k;
        int pb = 0;
        if (pp >= b1) pb = 1;
        if (pp >= b2) pb = 2;
        if (pp >= b3) pb = 3;
        atomicAdd(&sh[pb * LW + lab], 1);
      }
    }
    __syncthreads();
    for (int k = t; k < N_B * LW; k += blockDim.x)
      if (sh[k]) atomicAdd(&hist_full[k], sh[k]);
  } else if (bx < PB_HF + PB_PROP) {
    // ================= proposal histogram -> inst_hist ================
    if (t <= N_INST) sh[t] = prop_off[t];
    __syncthreads();
    const int blk = bx - PB_HF;
    const int4* pi4 = reinterpret_cast<const int4*>(prop_idx);
    const int nq = T_PROP / 2;
    for (int q = blk * blockDim.x + t; q < nq; q += PB_PROP * blockDim.x) {
      const int4 v = pi4[q];
      const int t0 = 2 * q, t1 = 2 * q + 1;
      const int il0 = inst_lab[v.y];
      const int il1 = inst_lab[v.w];
      int lo0 = 0, hi0 = N_INST + 1, lo1 = 0, hi1 = N_INST + 1;
      #pragma unroll
      for (int s = 0; s < 7; ++s) {
        const int m0 = (lo0 + hi0) >> 1;
        if (m0 <= N_INST && sh[m0] <= t0) lo0 = m0 + 1; else hi0 = m0;
        const int m1 = (lo1 + hi1) >> 1;
        if (m1 <= N_INST && sh[m1] <= t1) lo1 = m1 + 1; else hi1 = m1;
      }
      const int seg0 = min(lo0 - 1, N_INST - 1);
      const int seg1 = min(lo1 - 1, N_INST - 1);
      const int lab0 = (il0 == IGN) ? 0 : (il0 + 1);
      const int lab1 = (il1 == IGN) ? 0 : (il1 + 1);
      atomicAdd(&inst_hist[seg0 * LW + lab0], 1);
      atomicAdd(&inst_hist[seg1 * LW + lab1], 1);
    }
  } else if (bx < PB_PRE) {
    // ================= hist_mask over M points + meta ================
    for (int k = t; k < N_B * LW; k += blockDim.x) sh[k] = 0;
    __syncthreads();
    const int blk = bx - PB_HF - PB_PROP;
    const int4* oi4 = reinterpret_cast<const int4*>(obj_idx);
    const int4* bi4 = reinterpret_cast<const int4*>(batch_ids);
    ushort4* m4 = reinterpret_cast<ushort4*>(meta);
    const int nq = M_PTS / 4;
    for (int q = blk * blockDim.x + t; q < nq; q += PB_HM * blockDim.x) {
      const int4 o = oi4[q];
      const int4 b = bi4[q];
      const int il0 = inst_lab[o.x], il1 = inst_lab[o.y],
                il2 = inst_lab[o.z], il3 = inst_lab[o.w];
      const int sm0 = sem_lab[o.x], sm1 = sem_lab[o.y],
                sm2 = sem_lab[o.z], sm3 = sem_lab[o.w];
      const int ml0 = (il0 == IGN) ? 0 : (il0 + 1);
      const int ml1 = (il1 == IGN) ? 0 : (il1 + 1);
      const int ml2 = (il2 == IGN) ? 0 : (il2 + 1);
      const int ml3 = (il3 == IGN) ? 0 : (il3 + 1);
      atomicAdd(&sh[b.x * LW + ml0], 1);
      atomicAdd(&sh[b.y * LW + ml1], 1);
      atomicAdd(&sh[b.z * LW + ml2], 1);
      atomicAdd(&sh[b.w * LW + ml3], 1);
      if (write_meta) {
        ushort4 mm;
        mm.x = (unsigned short)(ml0 | (sm0 << 8) | (b.x << 13));
        mm.y = (unsigned short)(ml1 | (sm1 << 8) | (b.y << 13));
        mm.z = (unsigned short)(ml2 | (sm2 << 8) | (b.z << 13));
        mm.w = (unsigned short)(ml3 | (sm3 << 8) | (b.w << 13));
        m4[q] = mm;
      }
    }
    __syncthreads();
    for (int k = t; k < N_B * LW; k += blockDim.x)
      if (sh[k]) atomicAdd(&hist_mask[k], sh[k]);
  } else {
    // ================= per-point losses: LDS-staged 256-pt tile ============
    const int P0 = (bx - PB_PRE) * 256;
    // --- stage scores: 1280 float4 per tile, lane-contiguous ---
    {
      const float4* sc4 = reinterpret_cast<const float4*>(scores);
      const int base = P0 * 5;                        // f4 units (20 floats = 5 f4/pt)
      #pragma unroll
      for (int k = 0; k < 5; ++k) {
        const int fr = k * 256 + t;                   // 0..1279
        const int f  = base + fr;
        if (f < N_PTS * 5) {
          const float4 v = sc4[f];
          const int p_rel = fr / 5, c4 = fr % 5;
          float* dst = &s_f[p_rel * 21 + c4 * 4];
          dst[0] = v.x; dst[1] = v.y; dst[2] = v.z; dst[3] = v.w;
        }
      }
    }
    // --- stage coords & pt_off: 192 float4 each ---
    if (t < 192) {
      const float4* c4p = reinterpret_cast<const float4*>(coords);
      const float4* o4p = reinterpret_cast<const float4*>(pt_off);
      const int f = P0 * 3 / 4 + t;
      if (f < N_PTS * 3 / 4) {
        const float4 cv = c4p[f];
        const float4 ov = o4p[f];
        float* dc = &s_f[LDS_CO + 4 * t];
        float* dо = &s_f[LDS_OF + 4 * t];
        dc[0] = cv.x; dc[1] = cv.y; dc[2] = cv.z; dc[3] = cv.w;
        dо[0] = ov.x; dо[1] = ov.y; dо[2] = ov.z; dо[3] = ov.w;
      }
    }
    // --- stage info (keep comps 0..2 only): 576 float4 ---
    {
      const float4* i4p = reinterpret_cast<const float4*>(info);
      const int base = P0 * 9 / 4;
      #pragma unroll
      for (int k = 0; k < 3; ++k) {
        const int fr = k * 256 + t;
        if (fr < 576) {
          const int f = base + fr;
          if (f < N_PTS * 9 / 4) {
            const float4 v = i4p[f];
            const float vs[4] = { v.x, v.y, v.z, v.w };
            const int l = 4 * fr;
            #pragma unroll
            for (int i = 0; i < 4; ++i) {
              const int li = l + i;
              const int p_rel = li / 9, c = li % 9;
              if (c < 3) s_f[LDS_IN + p_rel * 3 + c] = vs[i];
            }
          }
        }
      }
    }
    __syncthreads();

    float s_nll = 0.f, s_cnt = 0.f, s_dist = 0.f, s_dir = 0.f, s_val = 0.f;
    const int p = P0 + t;
    if (p < N_PTS) {
      const int sl = sem_lab[p];      // lane-contiguous
      const int il = inst_lab[p];
      float x[C_CLS];
      #pragma unroll
      for (int c = 0; c < C_CLS; ++c) x[c] = s_f[t * 21 + c];
      float mx = x[0];
      #pragma unroll
      for (int c = 1; c < C_CLS; ++c) mx = fmaxf(mx, x[c]);
      float se = 0.f;
      #pragma unroll
      for (int c = 0; c < C_CLS; ++c) se += __expf(x[c] - mx);
      const float lse = mx + __logf(se);
      if (sl != IGN) { s_nll = lse - x[sl]; s_cnt = 1.f; }
      const float cx = s_f[LDS_CO + 3 * t + 0];
      const float cy = s_f[LDS_CO + 3 * t + 1];
      const float cz = s_f[LDS_CO + 3 * t + 2];
      const float ox = s_f[LDS_OF + 3 * t + 0];
      const float oy = s_f[LDS_OF + 3 * t + 1];
      const float oz = s_f[LDS_OF + 3 * t + 2];
      const float gx = s_f[LDS_IN + 3 * t + 0] - cx;
      const float gy = s_f[LDS_IN + 3 * t + 1] - cy;
      const float gz = s_f[LDS_IN + 3 * t + 2] - cz;
      if (il != IGN) {
        s_val  = 1.f;
        s_dist = fabsf(ox - gx) + fabsf(oy - gy) + fabsf(oz - gz);
        const float gn = sqrtf(gx * gx + gy * gy + gz * gz) + 1e-8f;
        const float pn = sqrtf(ox * ox + oy * oy + oz * oz) + 1e-8f;
        s_dir = -((gx * ox + gy * oy + gz * oz) / (gn * pn));
      }
    }
    __syncthreads();   // done with tile data; reuse LDS for reduction
    float* red = s_f;  // red[5][4]
    float vals[5] = { s_nll, s_cnt, s_dist, s_dir, s_val };
    const int lane = t & 63, wv = t >> 6;
    #pragma unroll
    for (int k = 0; k < 5; ++k) {
      const float r = waveSumF(vals[k]);
      if (lane == 0) red[k * 4 + wv] = r;
    }
    __syncthreads();
    if (t < 5) {
      const float s = red[t * 4 + 0] + red[t * 4 + 1] + red[t * 4 + 2] + red[t * 4 + 3];
      atomicAdd(&g[t], (double)s);
    }
  }
}

// ---------------------------------------------------------------------------
// K_MASK: per-block inline argmax->flags, then branchless float4 streaming.
// ---------------------------------------------------------------------------
template <bool USE_META>
__global__ __launch_bounds__(256) void k_mask(const float* __restrict__ logits,
                                              const unsigned short* __restrict__ meta,
                                              const int* __restrict__ obj_idx,
                                              const int* __restrict__ inst_lab,
                                              const int* __restrict__ sem_lab,
                                              const int* __restrict__ batch_ids,
                                              const int* __restrict__ inst_hist,
                                              const int* __restrict__ hist_full,
                                              const int* __restrict__ hist_mask,
                                              const int* __restrict__ inst_batch_ids,
                                              const int* __restrict__ inst_seg,
                                              int* __restrict__ flags,
                                              double* __restrict__ i_inter,
                                              double* __restrict__ i_up,
                                              double* __restrict__ i_ug,
                                              double* __restrict__ i_wbs,
                                              double* __restrict__ i_sn) {
  const int i = blockIdx.y;
  const int t = threadIdx.x;
  __shared__ int skey[4];
  __shared__ int sflag;
  {
    int key = 0;   // (cnt<<8) | (255-bin): max -> largest cnt, smallest bin
    if (t < LW) key = (inst_hist[i * LW + t] << 8) | (255 - t);
    key = waveMaxI(key);
    const int lane = t & 63, wv = t >> 6;
    if (lane == 0) skey[wv] = key;
    __syncthreads();
    if (t == 0) {
      const int k = max(max(skey[0], skey[1]), max(skey[2], skey[3]));
      const int m = 255 - (k & 0xFF);
      const int b = inst_batch_ids[i];
      const int seg = inst_seg[i];
      const bool skip = (m == 0) || (seg <= 3);
      const float num = (float)hist_mask[b * LW + m];
      const float den = (float)hist_full[b * LW + m];
      const float cover = (den > 0.f) ? (num / den) : 0.f;
      const bool pos = (!skip) && (cover > 0.3f);
      const int fl = m | (skip ? 0x100 : 0) | (pos ? 0x200 : 0) | (b << 10) | (seg << 12);
      sflag = fl;
      if (blockIdx.x == 0) flags[i] = fl;
    }
    __syncthreads();
  }
  const int fl = sflag;
  const int  mode_i = fl & 0xFF;
  const bool skip   = (fl >> 8) & 1;
  const bool pos    = (fl >> 9) & 1;
  const int  bi     = (fl >> 10) & 3;
  const int  seg    = (fl >> 12) & 31;

  float inter = 0.f, up = 0.f, ug = 0.f, wbs = 0.f, sn = 0.f;

  if (USE_META) {
    const float4* row4 = reinterpret_cast<const float4*>(logits + (size_t)i * M_PTS);
    const ushort4* m4  = reinterpret_cast<const ushort4*>(meta);
    const int nq = M_PTS / 4;
    const int step = gridDim.x * blockDim.x;
    for (int q = blockIdx.x * blockDim.x + t; q < nq; q += 2 * step) {
      const int q2 = q + step;
      const bool has2 = q2 < nq;
      const float4  xa = row4[q];
      const ushort4 da = m4[q];
      float4  xb = xa; ushort4 db = da;
      if (has2) { xb = row4[q2]; db = m4[q2]; }
      const float xs[8] = { xa.x, xa.y, xa.z, xa.w, xb.x, xb.y, xb.z, xb.w };
      const int   ds[8] = { da.x, da.y, da.z, da.w, db.x, db.y, db.z, db.w };
      const int nk = has2 ? 8 : 4;
      #pragma unroll
      for (int k = 0; k < 8; ++k) {
        if (k >= nk) break;
        const int md = ds[k];
        const int ml = md & 0xFF;
        const int sm = (md >> 8) & 31;
        const int b  = (md >> 13) & 3;
        const bool w  = (b == bi) && (skip || (sm == seg));
        const bool gt = pos && (ml == mode_i);
        const float x  = xs[k];
        const float e  = __expf(-fabsf(x));
        const float r  = __builtin_amdgcn_rcpf(1.f + e);
        const float pr = (x >= 0.f) ? r : e * r;            // sigmoid
        const float sp = fmaxf(x, 0.f) + __logf(1.f + e);   // softplus
        const float wf = w ? 1.f : 0.f;
        const float gf = gt ? 1.f : 0.f;
        up    += wf * pr * pr;
        wbs   += wf;
        sn    += wf * (sp - gf * x);
        inter += wf * gf * pr;
        ug    += wf * gf;
      }
    }
  } else {
    const float* row = logits + (size_t)i * M_PTS;
    for (int j = blockIdx.x * blockDim.x + t; j < M_PTS; j += gridDim.x * blockDim.x) {
      const int o  = obj_idx[j];
      const int il = inst_lab[o];
      const int ml = (il == IGN) ? 0 : (il + 1);
      const int sm = sem_lab[o];
      const int b  = batch_ids[j];
      const bool w  = (b == bi) && (skip || (sm == seg));
      const bool gt = pos && (ml == mode_i);
      const float x  = row[j];
      const float e  = __expf(-fabsf(x));
      const float r  = __builtin_amdgcn_rcpf(1.f + e);
      const float pr = (x >= 0.f) ? r : e * r;
      const float sp = fmaxf(x, 0.f) + __logf(1.f + e);
      const float wf = w ? 1.f : 0.f;
      const float gf = gt ? 1.f : 0.f;
      up    += wf * pr * pr;
      wbs   += wf;
      sn    += wf * (sp - gf * x);
      inter += wf * gf * pr;
      ug    += wf * gf;
    }
  }

  __shared__ float red[5][4];
  float vals[5] = { inter, up, ug, wbs, sn };
  const int lane = t & 63, wv = t >> 6;
  #pragma unroll
  for (int k = 0; k < 5; ++k) {
    const float r = waveSumF(vals[k]);
    if (lane == 0) red[k][wv] = r;
  }
  __syncthreads();
  if (t < 5) {
    const float s = red[t][0] + red[t][1] + red[t][2] + red[t][3];
    double* dst = (t == 0) ? (i_inter + i)
                : (t == 1) ? (i_up + i)
                : (t == 2) ? (i_ug + i)
                : (t == 3) ? (i_wbs + i)
                           : (i_sn + i);
    atomicAdd(dst, (double)s);
  }
}

// ---------------------------------------------------------------------------
// K_FINAL
// ---------------------------------------------------------------------------
__global__ void k_final(const double* __restrict__ g,
                        const double* __restrict__ i_inter,
                        const double* __restrict__ i_up,
                        const double* __restrict__ i_ug,
                        const double* __restrict__ i_wbs,
                        const double* __restrict__ i_sn,
                        const int* __restrict__ flags,
                        const int* __restrict__ epoch,
                        float* __restrict__ out) {
  if (threadIdx.x != 0 || blockIdx.x != 0) return;
  double loss = g[0] / fmax(g[1], 1.0);            // semantic
  const double vsum = g[4] + 1e-6;
  loss += g[2] / vsum + g[3] / vsum;               // offset norm + dir
  if (epoch[0] > PREP) {
    double sn = 0.0, wsum = 0.0, dice = 0.0, dcnt = 0.0;
    for (int i = 0; i < N_INST; ++i) {
      wsum += i_wbs[i];
      sn   += i_sn[i];
      const bool skip = (flags[i] >> 8) & 1;
      if (!skip && i_wbs[i] > 0.0) {
        const double un = i_up[i] + i_ug[i] + 1e-5;
        dice += 1.0 - 2.0 * i_inter[i] / un;
        dcnt += 1.0;
      }
    }
    loss += sn / (wsum + 1e-6) + dice / (dcnt + 1e-6);
  }
  out[0] = (float)loss;
}

} // anonymous namespace

extern "C" void kernel_launch(void* const* d_in, const int* in_sizes, int n_in,
                              void* d_out, int out_size, void* d_ws, size_t ws_size,
                              hipStream_t stream) {
  const float* semantic_scores  = (const float*)d_in[0];
  const float* pt_offsets       = (const float*)d_in[1];
  const float* instance_info    = (const float*)d_in[2];
  const float* coords           = (const float*)d_in[3];
  const float* mask_logits      = (const float*)d_in[4];
  const int*   semantic_labels  = (const int*)d_in[5];
  const int*   instance_labels  = (const int*)d_in[6];
  const int*   object_idxs      = (const int*)d_in[7];
  const int*   proposals_idx    = (const int*)d_in[8];
  const int*   proposals_off    = (const int*)d_in[9];
  const int*   inst_batch_ids   = (const int*)d_in[10];
  const int*   batch_ids        = (const int*)d_in[11];
  const int*   batch_offsets    = (const int*)d_in[12];
  const int*   inst_seg         = (const int*)d_in[13];
  const int*   epoch            = (const int*)d_in[14];
  float* out = (float*)d_out;

  char* w = (char*)d_ws;
  double* g        = (double*)(w + OFF_G);
  double* i_inter  = (double*)(w + OFF_INTER);
  double* i_up     = (double*)(w + OFF_UP);
  double* i_ug     = (double*)(w + OFF_UG);
  double* i_wbs    = (double*)(w + OFF_WBS);
  double* i_sn     = (double*)(w + OFF_SN);
  int* hist_full   = (int*)(w + OFF_HFULL);
  int* hist_mask   = (int*)(w + OFF_HMASK);
  int* inst_hist   = (int*)(w + OFF_IHIST);
  int* flags       = (int*)(w + OFF_FLAGS);
  unsigned short* meta = (unsigned short*)(w + OFF_META);

  const bool use_meta = (ws_size >= WS_REQUIRED);

  (void)hipMemsetAsync(d_ws, 0, ZERO_BYTES, stream);

  k_A<<<A_BLOCKS, 256, 0, stream>>>(semantic_scores, pt_offsets, instance_info, coords,
                                    semantic_labels, instance_labels, object_idxs,
                                    batch_ids, proposals_idx, proposals_off, batch_offsets,
                                    g, hist_full, hist_mask, inst_hist, meta,
                                    use_meta ? 1 : 0);

  dim3 mgrid(20, N_INST);
  if (use_meta) {
    k_mask<true><<<mgrid, 256, 0, stream>>>(mask_logits, meta, object_idxs, instance_labels,
                                            semantic_labels, batch_ids, inst_hist,
                                            hist_full, hist_mask, inst_batch_ids, inst_seg,
                                            flags, i_inter, i_up, i_ug, i_wbs, i_sn);
  } else {
    k_mask<false><<<mgrid, 256, 0, stream>>>(mask_logits, meta, object_idxs, instance_labels,
                                             semantic_labels, batch_ids, inst_hist,
                                             hist_full, hist_mask, inst_batch_ids, inst_seg,
                                             flags, i_inter, i_up, i_ug, i_wbs, i_sn);
  }
  k_final<<<1, 64, 0, stream>>>(g, i_inter, i_up, i_ug, i_wbs, i_sn, flags, epoch, out);
}